// Round 2
// baseline (804.520 us; speedup 1.0000x reference)
//
#include <hip/hip_runtime.h>
#include <stdint.h>

typedef _Float16 f16;
typedef _Float16 f16x8 __attribute__((ext_vector_type(8)));
typedef float    f32x4 __attribute__((ext_vector_type(4)));

__device__ __forceinline__ void gload16(const void* g, void* l) {
  __builtin_amdgcn_global_load_lds(
      (__attribute__((address_space(1))) void*)g,
      (__attribute__((address_space(3))) void*)l, 16, 0, 0);
}

// ---------------------------------------------------------------------------
// GEMM: C[M][N] = A[M][lda] * Bt[N][ldb]^T   (f16 inputs, fp32 accum)
// 128x128 tile, BK=64, 4 waves (2x2), mfma_f32_16x16x32_f16.
// WRAP: A column index = k & 1023 (for the bucket GEMM's hhi re-read).
// EPI: 1 = f16 plain | 2 = fp32 c+bias+add1 | 3 = f16 relu(c+bias) |
//      4 = fp32 0.5*(c+bias+add1+add2) | 6 = per-head bucket argmax
// ---------------------------------------------------------------------------
template<int EPI, int WRAP>
__global__ __launch_bounds__(256)
void gemm_bt(const f16* __restrict__ A, int lda,
             const f16* __restrict__ Bt, int ldb,
             int K, int N,
             float* __restrict__ outf, f16* __restrict__ outh,
             const float* __restrict__ bias,
             const float* __restrict__ add1,
             const float* __restrict__ add2,
             int* __restrict__ bucket_out)
{
  __shared__ __align__(16) f16 sA[128 * 64];
  __shared__ __align__(16) f16 sB[128 * 64];
  const int tid  = threadIdx.x;
  const int lane = tid & 63;
  const int wv   = tid >> 6;
  const int wm   = wv >> 1, wn = wv & 1;
  const int l15  = lane & 15, l4 = lane >> 4;
  const long bm0 = (long)blockIdx.y * 128;
  const long bn0 = (long)blockIdx.x * 128;

  f32x4 acc[4][4];
#pragma unroll
  for (int i = 0; i < 4; ++i)
#pragma unroll
    for (int j = 0; j < 4; ++j) acc[i][j] = f32x4{0.f, 0.f, 0.f, 0.f};

  const int rs = tid >> 3;            // 0..31 (row within a 32-row round)
  const int cs = tid & 7;             // lds chunk slot
  const int cg = cs ^ (rs & 7);       // swizzled global chunk

  const int nkt = K >> 6;
  for (int kt = 0; kt < nkt; ++kt) {
    __syncthreads();
    long ka = (long)kt * 64 + cg * 8;
    if (WRAP) ka &= 1023;             // 64-blocks never straddle 1024
#pragma unroll
    for (int rd = 0; rd < 4; ++rd) {
      const int row = rs + rd * 32;
      gload16(A + (bm0 + row) * lda + ka, &sA[row * 64 + cs * 8]);
    }
    const long kb = (long)kt * 64 + cg * 8;
#pragma unroll
    for (int rd = 0; rd < 4; ++rd) {
      const int row = rs + rd * 32;
      gload16(Bt + (bn0 + row) * ldb + kb, &sB[row * 64 + cs * 8]);
    }
    __syncthreads();   // compiler drains vmcnt before s_barrier
#pragma unroll
    for (int kk = 0; kk < 2; ++kk) {
      f16x8 af[4], bfr[4];
#pragma unroll
      for (int mt = 0; mt < 4; ++mt) {
        const int row = wm * 64 + mt * 16 + l15;
        const int c = kk * 4 + l4;
        af[mt] = *(const f16x8*)&sA[row * 64 + ((c ^ (row & 7)) << 3)];
      }
#pragma unroll
      for (int nt = 0; nt < 4; ++nt) {
        const int row = wn * 64 + nt * 16 + l15;
        const int c = kk * 4 + l4;
        bfr[nt] = *(const f16x8*)&sB[row * 64 + ((c ^ (row & 7)) << 3)];
      }
#pragma unroll
      for (int mt = 0; mt < 4; ++mt)
#pragma unroll
        for (int nt = 0; nt < 4; ++nt)
          acc[mt][nt] = __builtin_amdgcn_mfma_f32_16x16x32_f16(af[mt], bfr[nt], acc[mt][nt], 0, 0, 0);
    }
  }

  if constexpr (EPI == 6) {
    // Each wave's 64x64 sub-tile = one head's full 64 r-columns.
    const int head = (int)(bn0 >> 6) + wn;
#pragma unroll
    for (int mt = 0; mt < 4; ++mt)
#pragma unroll
      for (int r = 0; r < 4; ++r) {
        float bv = -1e30f, mv = 1e30f;
        int bi = 127, mi = 127;
#pragma unroll
        for (int nt = 0; nt < 4; ++nt) {
          const float v = acc[mt][nt][r];
          const int idx = nt * 16 + l15;
          if (v > bv) { bv = v; bi = idx; }   // nt ascending -> first occurrence
          if (v < mv) { mv = v; mi = idx; }
        }
#pragma unroll
        for (int mk = 1; mk < 16; mk <<= 1) {
          const float ov = __shfl_xor(bv, mk); const int oi = __shfl_xor(bi, mk);
          if (ov > bv || (ov == bv && oi < bi)) { bv = ov; bi = oi; }
          const float ou = __shfl_xor(mv, mk); const int ui = __shfl_xor(mi, mk);
          if (ou < mv || (ou == mv && ui < mi)) { mv = ou; mi = ui; }
        }
        if (l15 == 0) {
          const int bucket = (bv >= -mv) ? bi : 64 + mi;
          const long grow = bm0 + wm * 64 + mt * 16 + l4 * 4 + r;
          const int bb = (int)(grow >> 12), tt = (int)(grow & 4095);
          bucket_out[((long)bb * 8 + head) * 4096 + tt] = bucket;
        }
      }
    return;
  }

#pragma unroll
  for (int mt = 0; mt < 4; ++mt)
#pragma unroll
    for (int nt = 0; nt < 4; ++nt)
#pragma unroll
      for (int r = 0; r < 4; ++r) {
        const long grow = bm0 + wm * 64 + mt * 16 + l4 * 4 + r;
        const long gcol = bn0 + wn * 64 + nt * 16 + l15;
        const long idx  = grow * (long)N + gcol;
        const float c = acc[mt][nt][r];
        if constexpr (EPI == 1) {
          outh[idx] = (f16)c;
        } else if constexpr (EPI == 2) {
          outf[idx] = c + bias[gcol] + add1[idx];
        } else if constexpr (EPI == 3) {
          outh[idx] = (f16)fmaxf(c + bias[gcol], 0.f);
        } else if constexpr (EPI == 4) {
          outf[idx] = 0.5f * (c + bias[gcol] + add1[idx] + add2[idx]);
        }
      }
}

// ---------------------------------------------------------------------------
// LayerNorm over D=512, one wave per row. split: writes [hi | (y-hi)*64]
// at row stride ldo (for the high-precision bucket GEMM).
// ---------------------------------------------------------------------------
__global__ __launch_bounds__(256)
void ln_kernel(const float* __restrict__ in, const float* __restrict__ gam,
               const float* __restrict__ bet, f16* __restrict__ out,
               int ldo, int split)
{
  const long row = (long)blockIdx.x * 4 + (threadIdx.x >> 6);
  const int lane = threadIdx.x & 63;
  const float4* p = (const float4*)(in + row * 512);
  const float4 a = p[lane * 2], b = p[lane * 2 + 1];
  float xv[8] = {a.x, a.y, a.z, a.w, b.x, b.y, b.z, b.w};
  float s = 0.f;
#pragma unroll
  for (int i = 0; i < 8; ++i) s += xv[i];
#pragma unroll
  for (int m = 32; m; m >>= 1) s += __shfl_xor(s, m);
  const float mean = s * (1.f / 512.f);
  float vs = 0.f;
#pragma unroll
  for (int i = 0; i < 8; ++i) { const float d = xv[i] - mean; vs += d * d; }
#pragma unroll
  for (int m = 32; m; m >>= 1) vs += __shfl_xor(vs, m);
  const float rstd = 1.f / sqrtf(vs * (1.f / 512.f) + 1e-5f);
  const float4* gp = (const float4*)gam;
  const float4* bp = (const float4*)bet;
  const float4 g0 = gp[lane * 2], g1 = gp[lane * 2 + 1];
  const float4 b0 = bp[lane * 2], b1 = bp[lane * 2 + 1];
  const float gg[8] = {g0.x, g0.y, g0.z, g0.w, g1.x, g1.y, g1.z, g1.w};
  const float bb[8] = {b0.x, b0.y, b0.z, b0.w, b1.x, b1.y, b1.z, b1.w};
  f16x8 vh, vl;
#pragma unroll
  for (int i = 0; i < 8; ++i) {
    const float y = (xv[i] - mean) * rstd * gg[i] + bb[i];
    const f16 hi = (f16)y;
    vh[i] = hi;
    vl[i] = (f16)((y - (float)hi) * 64.f);
  }
  f16* o = out + row * ldo + lane * 8;
  *(f16x8*)o = vh;
  if (split) *(f16x8*)(o + 512) = vl;
}

// ---------------------------------------------------------------------------
// Transpose fp32 [K][N] -> f16 [N][K] (weights, small).
// ---------------------------------------------------------------------------
__global__ __launch_bounds__(256)
void transpose_f16(const float* __restrict__ src, f16* __restrict__ dst, int K, int N)
{
  __shared__ float tile[32][33];
  const int tx = threadIdx.x & 31, ty = threadIdx.x >> 5;
  const long k0 = (long)blockIdx.y * 32, n0 = (long)blockIdx.x * 32;
#pragma unroll
  for (int i = 0; i < 4; ++i)
    tile[ty + i * 8][tx] = src[(k0 + ty + i * 8) * N + n0 + tx];
  __syncthreads();
#pragma unroll
  for (int i = 0; i < 4; ++i)
    dst[(n0 + ty + i * 8) * K + k0 + tx] = (f16)tile[tx][ty + i * 8];
}

// ---------------------------------------------------------------------------
// Bucket-GEMM B: Wr[k][n] = sum_d w_qk[k][h*64+d]*rot[d][i], n = h*64+i.
// Rows of bth[512][1536]: [Wr_hi*64 | Wr_hi | Wr_lo*64]  (global x64 scale,
// argmax-invariant; pairs with A = [hhi | hlo*64 | hhi(wrap)]).
// ---------------------------------------------------------------------------
__global__ __launch_bounds__(256)
void whash_kernel(const float* __restrict__ wqk, const float* __restrict__ rot,
                  f16* __restrict__ bth)
{
  const int kk = blockIdx.x;                     // 0..511
  const int n  = blockIdx.y * 256 + threadIdx.x; // 0..511
  const int h = n >> 6, i = n & 63;
  float s = 0.f;
  for (int d = 0; d < 64; ++d)
    s += wqk[kk * 512 + h * 64 + d] * rot[d * 64 + i];
  const f16 whi = (f16)s;
  const float whif = (float)whi;
  bth[(long)n * 1536 + kk]        = (f16)(whif * 64.f);   // exact (pow2 scale)
  bth[(long)n * 1536 + 512 + kk]  = whi;
  bth[(long)n * 1536 + 1024 + kk] = (f16)((s - whif) * 64.f);
}

// ---------------------------------------------------------------------------
// Stable counting sort by (bucket, t) per bh. One 256-thread block per bh.
// sticker[pos] = original t.
// ---------------------------------------------------------------------------
__global__ __launch_bounds__(256)
void sort_kernel(const int* __restrict__ buckets, int* __restrict__ sticker)
{
  __shared__ int bkt[4096];
  __shared__ unsigned int cnts[64][128];
  __shared__ unsigned char rnk[4096];
  __shared__ int tot[128];
  __shared__ int base[128];
  const int bh = blockIdx.x;
  const int tid = threadIdx.x;
  const int lane = tid & 63, wv = tid >> 6;

  for (int i = tid; i < 4096; i += 256) bkt[i] = buckets[(long)bh * 4096 + i] & 127;
  for (int i = tid; i < 64 * 128; i += 256) ((unsigned int*)cnts)[i] = 0u;
  __syncthreads();

  for (int it = 0; it < 16; ++it) {
    const int c = wv * 16 + it;
    const int t = c * 64 + lane;
    const int b = bkt[t];
    unsigned long long m = ~0ull;
#pragma unroll
    for (int k = 0; k < 7; ++k) {
      const bool bit = (b >> k) & 1;
      const unsigned long long bal = __ballot(bit);
      m &= bit ? bal : ~bal;
    }
    const int rk = (int)__popcll(m & ((1ull << lane) - 1ull));
    rnk[t] = (unsigned char)rk;
    if (rk == 0) cnts[c][b] = (unsigned int)__popcll(m);
  }
  __syncthreads();

  if (tid < 128) {
    unsigned int run = 0;
    for (int c = 0; c < 64; ++c) {
      const unsigned int x = cnts[c][tid];
      cnts[c][tid] = run;
      run += x;
    }
    tot[tid] = (int)run;
  }
  __syncthreads();
  if (tid == 0) {
    int run = 0;
    for (int b = 0; b < 128; ++b) { base[b] = run; run += tot[b]; }
  }
  __syncthreads();

  for (int it = 0; it < 16; ++it) {
    const int c = wv * 16 + it;
    const int t = c * 64 + lane;
    const int b = bkt[t];
    const int pos = base[b] + (int)cnts[c][b] + (int)rnk[t];
    sticker[(long)bh * 4096 + pos] = t;
  }
}

// ---------------------------------------------------------------------------
// LSH chunk attention. One wave per (chunk ci, bh). qkv f16 [32768][1024]
// (qk cols 0..511, v cols 512..1023). Output o f16 [32768][512].
// ---------------------------------------------------------------------------
__global__ __launch_bounds__(64)
void attn_kernel(const f16* __restrict__ qkv, const int* __restrict__ sticker,
                 f16* __restrict__ o)
{
  __shared__ __align__(16) f16 sQ[32][72];
  __shared__ __align__(16) f16 sK[64][72];
  __shared__ __align__(16) f16 sVt[64][72];
  __shared__ __align__(16) f16 sP[32][72];
  __shared__ int spos[64];

  const int lane = threadIdx.x;
  const int ci = blockIdx.x, bh = blockIdx.y;
  const int b = bh >> 3, h = bh & 7;
  const int pc = (ci + 127) & 127;
  const int l15 = lane & 15, l4 = lane >> 4;

  spos[lane] = sticker[bh * 4096 + ((lane < 32) ? (ci * 32 + lane) : (pc * 32 + lane - 32))] & 4095;
  __syncthreads();

  const f16* qb = qkv + (long)b * 4096 * 1024 + h * 64 + lane;
  for (int rc = 0; rc < 4; ++rc) {
    float qv[16], vv[16];
#pragma unroll
    for (int j = 0; j < 16; ++j) {
      const f16* p = qb + (long)spos[rc * 16 + j] * 1024;
      qv[j] = (float)p[0];
      vv[j] = (float)p[512];
    }
#pragma unroll
    for (int j = 0; j < 16; ++j) {
      const int rr = rc * 16 + j;
      float s = qv[j] * qv[j];
#pragma unroll
      for (int m = 32; m; m >>= 1) s += __shfl_xor(s, m);
      const float inv = 1.f / fmaxf(sqrtf(s), 1e-12f);
      sK[rr][lane] = (f16)(qv[j] * inv);
      sVt[lane][rr] = (f16)vv[j];
      if (rr < 32) sQ[rr][lane] = (f16)qv[j];
    }
  }
  __syncthreads();

  f32x4 acc[2][4];
#pragma unroll
  for (int i = 0; i < 2; ++i)
#pragma unroll
    for (int j = 0; j < 4; ++j) acc[i][j] = f32x4{0.f, 0.f, 0.f, 0.f};

#pragma unroll
  for (int kk = 0; kk < 2; ++kk) {
    f16x8 aq[2], bk[4];
#pragma unroll
    for (int mt = 0; mt < 2; ++mt)
      aq[mt] = *(const f16x8*)&sQ[mt * 16 + l15][kk * 32 + l4 * 8];
#pragma unroll
    for (int nt = 0; nt < 4; ++nt)
      bk[nt] = *(const f16x8*)&sK[nt * 16 + l15][kk * 32 + l4 * 8];
#pragma unroll
    for (int mt = 0; mt < 2; ++mt)
#pragma unroll
      for (int nt = 0; nt < 4; ++nt)
        acc[mt][nt] = __builtin_amdgcn_mfma_f32_16x16x32_f16(aq[mt], bk[nt], acc[mt][nt], 0, 0, 0);
  }

  float pinv[2][4];
#pragma unroll
  for (int mt = 0; mt < 2; ++mt)
#pragma unroll
    for (int r = 0; r < 4; ++r) {
      const int row_i = mt * 16 + l4 * 4 + r;
      float mx = -1e30f;
#pragma unroll
      for (int nt = 0; nt < 4; ++nt) {
        float v = acc[mt][nt][r] * 0.125f;      // * D^-0.5
        if (nt * 16 + l15 == row_i) v = -5e4f;  // self-mask (diagonal only)
        acc[mt][nt][r] = v;
        mx = fmaxf(mx, v);
      }
#pragma unroll
      for (int m = 8; m; m >>= 1) mx = fmaxf(mx, __shfl_xor(mx, m));
      float ssum = 0.f;
#pragma unroll
      for (int nt = 0; nt < 4; ++nt) {
        const float pe = expf(acc[mt][nt][r] - mx);
        ssum += pe;
        sP[row_i][nt * 16 + l15] = (f16)pe;
      }
#pragma unroll
      for (int m = 8; m; m >>= 1) ssum += __shfl_xor(ssum, m);
      pinv[mt][r] = 1.f / ssum;
    }
  __syncthreads();

  f32x4 pacc[2][4];
#pragma unroll
  for (int i = 0; i < 2; ++i)
#pragma unroll
    for (int j = 0; j < 4; ++j) pacc[i][j] = f32x4{0.f, 0.f, 0.f, 0.f};

#pragma unroll
  for (int kk = 0; kk < 2; ++kk) {
    f16x8 ap[2], bv[4];
#pragma unroll
    for (int mt = 0; mt < 2; ++mt)
      ap[mt] = *(const f16x8*)&sP[mt * 16 + l15][kk * 32 + l4 * 8];
#pragma unroll
    for (int nt = 0; nt < 4; ++nt)
      bv[nt] = *(const f16x8*)&sVt[nt * 16 + l15][kk * 32 + l4 * 8];
#pragma unroll
    for (int mt = 0; mt < 2; ++mt)
#pragma unroll
      for (int nt = 0; nt < 4; ++nt)
        pacc[mt][nt] = __builtin_amdgcn_mfma_f32_16x16x32_f16(ap[mt], bv[nt], pacc[mt][nt], 0, 0, 0);
  }

  const long ob = (long)b * 4096 * 512 + h * 64;
#pragma unroll
  for (int mt = 0; mt < 2; ++mt)
#pragma unroll
    for (int r = 0; r < 4; ++r) {
      const int row_i = mt * 16 + l4 * 4 + r;
      const long t = spos[row_i];
      const float sc = pinv[mt][r];
#pragma unroll
      for (int nt = 0; nt < 4; ++nt)
        o[ob + t * 512 + nt * 16 + l15] = (f16)(pacc[mt][nt][r] * sc);
    }
}

// ---------------------------------------------------------------------------
extern "C" void kernel_launch(void* const* d_in, const int* in_sizes, int n_in,
                              void* d_out, int out_size, void* d_ws, size_t ws_size,
                              hipStream_t stream)
{
  const float* x     = (const float*)d_in[0];
  const float* w_qk  = (const float*)d_in[1];
  const float* w_v   = (const float*)d_in[2];
  const float* w_out = (const float*)d_in[3];
  const float* b_out = (const float*)d_in[4];
  const float* ln1g  = (const float*)d_in[5];
  const float* ln1b  = (const float*)d_in[6];
  const float* w_ff1 = (const float*)d_in[7];
  const float* b_ff1 = (const float*)d_in[8];
  const float* w_ff2 = (const float*)d_in[9];
  const float* b_ff2 = (const float*)d_in[10];
  const float* ln2g  = (const float*)d_in[11];
  const float* ln2b  = (const float*)d_in[12];
  const float* rot   = (const float*)d_in[13];
  float* out = (float*)d_out;   // also serves as y1 (read-before-write in EPI4)

  char* ws = (char*)d_ws;
  // [0,64M):   hsplit f16 [32768][1024]  -> later o[0,32M) + h2[32M,64M)
  // [64M,128M): qkv f16 [32768][1024]    -> later abuf f16 [8192][2048] (32M)
  // [128M,137M): weights + buckets + sticker
  f16* hsplit = (f16*)ws;
  f16* o_buf  = (f16*)ws;                       // [32768][512]
  f16* h2     = (f16*)(ws + 33554432);          // [32768][512]
  f16* qkv    = (f16*)(ws + 67108864);          // [32768][1024]
  f16* abuf   = (f16*)(ws + 67108864);          // [8192][2048] per FFN chunk
  char* W0 = ws + 134217728;
  f16* wqkvT = (f16*)W0;                        // [1024][512]
  f16* woutT = (f16*)(W0 + 1048576);            // [512][512]
  f16* wff1T = (f16*)(W0 + 1572864);            // [2048][512]
  f16* wff2T = (f16*)(W0 + 3670016);            // [512][2048]
  f16* bth   = (f16*)(W0 + 5767168);            // [512][1536]
  int* buckets = (int*)(W0 + 7340032);          // [64][4096]
  int* sticker = (int*)(W0 + 8388608);          // [64][4096]

  const dim3 b256(256);
  // weight prep
  transpose_f16<<<dim3(16, 16), b256, 0, stream>>>(w_qk,  wqkvT,             512, 512);
  transpose_f16<<<dim3(16, 16), b256, 0, stream>>>(w_v,   wqkvT + 512 * 512, 512, 512);
  transpose_f16<<<dim3(16, 16), b256, 0, stream>>>(w_out, woutT,             512, 512);
  transpose_f16<<<dim3(64, 16), b256, 0, stream>>>(w_ff1, wff1T,             512, 2048);
  transpose_f16<<<dim3(16, 64), b256, 0, stream>>>(w_ff2, wff2T,             2048, 512);
  whash_kernel<<<dim3(512, 2), b256, 0, stream>>>(w_qk, rot, bth);
  // LN1: writes [hhi | hlo*64], lda 1024
  ln_kernel<<<dim3(8192), b256, 0, stream>>>(x, ln1g, ln1b, hsplit, 1024, 1);
  // qkv = h1 @ [w_qk | w_v]  (f16 out, K=512 reads hhi block)
  gemm_bt<1, 0><<<dim3(8, 256), b256, 0, stream>>>(hsplit, 1024, wqkvT, 512, 512, 1024,
                                                   nullptr, qkv, nullptr, nullptr, nullptr, nullptr);
  // buckets: r*64 = h1 @ Wr via 3-term split (K=1536, A wraps), fused argmax
  gemm_bt<6, 1><<<dim3(4, 256), b256, 0, stream>>>(hsplit, 1024, bth, 1536, 1536, 512,
                                                   nullptr, nullptr, nullptr, nullptr, nullptr, buckets);
  sort_kernel<<<dim3(64), b256, 0, stream>>>(buckets, sticker);
  attn_kernel<<<dim3(128, 64), dim3(64), 0, stream>>>(qkv, sticker, o_buf);
  // y1 (in d_out) = x + o @ w_out + b_out
  gemm_bt<2, 0><<<dim3(4, 256), b256, 0, stream>>>(o_buf, 512, woutT, 512, 512, 512,
                                                   out, nullptr, b_out, x, nullptr, nullptr);
  ln_kernel<<<dim3(8192), b256, 0, stream>>>(out, ln2g, ln2b, h2, 512, 0);
  // FFN in 4 row-chunks of 8192 (abuf is 32 MB, reused)
  for (int c = 0; c < 4; ++c) {
    const long roff = (long)c * 8192;
    gemm_bt<3, 0><<<dim3(16, 64), b256, 0, stream>>>(h2 + roff * 512, 512, wff1T, 512, 512, 2048,
                                                     nullptr, abuf, b_ff1, nullptr, nullptr, nullptr);
    gemm_bt<4, 0><<<dim3(4, 64), b256, 0, stream>>>(abuf, 2048, wff2T, 2048, 2048, 512,
                                                    out + roff * 512, nullptr, b_ff2,
                                                    x + roff * 512, out + roff * 512, nullptr);
  }
}

// Round 3
// 589.475 us; speedup vs baseline: 1.3648x; 1.3648x over previous
//
#include <hip/hip_runtime.h>
#include <stdint.h>

typedef _Float16 f16;
typedef _Float16 f16x8 __attribute__((ext_vector_type(8)));
typedef float    f32x4 __attribute__((ext_vector_type(4)));

__device__ __forceinline__ void gload16(const void* g, void* l) {
  __builtin_amdgcn_global_load_lds(
      (__attribute__((address_space(1))) void*)g,
      (__attribute__((address_space(3))) void*)l, 16, 0, 0);
}

// ---------------------------------------------------------------------------
// GEMM: C[M][N] = A[M][lda] * Bt[N][ldb]^T   (f16 inputs, fp32 accum)
// 128x128 tile, BK=64, 4 waves (2x2), mfma_f32_16x16x32_f16.
// WRAP: A column index = k & 1023 (bucket GEMM hhi re-read).
// EPI: 2 = fp32 c+bias+add1 | 3 = f16 relu(c+bias) |
//      4 = fp32 0.5*(c+bias+add1+add2) | 5 = f16 sorted scatter (qkv) |
//      6 = per-head bucket argmax
// ---------------------------------------------------------------------------
template<int EPI, int WRAP>
__global__ __launch_bounds__(256)
void gemm_bt(const f16* __restrict__ A, int lda,
             const f16* __restrict__ Bt, int ldb,
             int K, int N,
             float* __restrict__ outf, f16* __restrict__ outh,
             f16* __restrict__ outh2,
             const float* __restrict__ bias,
             const float* __restrict__ add1,
             const float* __restrict__ add2,
             int* __restrict__ ibuf)
{
  __shared__ __align__(16) f16 sA[128 * 64];
  __shared__ __align__(16) f16 sB[128 * 64];
  const int tid  = threadIdx.x;
  const int lane = tid & 63;
  const int wv   = tid >> 6;
  const int wm   = wv >> 1, wn = wv & 1;
  const int l15  = lane & 15, l4 = lane >> 4;
  const long bm0 = (long)blockIdx.y * 128;
  const long bn0 = (long)blockIdx.x * 128;

  f32x4 acc[4][4];
#pragma unroll
  for (int i = 0; i < 4; ++i)
#pragma unroll
    for (int j = 0; j < 4; ++j) acc[i][j] = f32x4{0.f, 0.f, 0.f, 0.f};

  const int rs = tid >> 3;            // 0..31
  const int cs = tid & 7;
  const int cg = cs ^ (rs & 7);       // swizzled global chunk

  const int nkt = K >> 6;
  for (int kt = 0; kt < nkt; ++kt) {
    __syncthreads();
    long ka = (long)kt * 64 + cg * 8;
    if (WRAP) ka &= 1023;
#pragma unroll
    for (int rd = 0; rd < 4; ++rd) {
      const int row = rs + rd * 32;
      gload16(A + (bm0 + row) * lda + ka, &sA[row * 64 + cs * 8]);
    }
    const long kb = (long)kt * 64 + cg * 8;
#pragma unroll
    for (int rd = 0; rd < 4; ++rd) {
      const int row = rs + rd * 32;
      gload16(Bt + (bn0 + row) * ldb + kb, &sB[row * 64 + cs * 8]);
    }
    __syncthreads();
#pragma unroll
    for (int kk = 0; kk < 2; ++kk) {
      f16x8 af[4], bfr[4];
#pragma unroll
      for (int mt = 0; mt < 4; ++mt) {
        const int row = wm * 64 + mt * 16 + l15;
        const int c = kk * 4 + l4;
        af[mt] = *(const f16x8*)&sA[row * 64 + ((c ^ (row & 7)) << 3)];
      }
#pragma unroll
      for (int nt = 0; nt < 4; ++nt) {
        const int row = wn * 64 + nt * 16 + l15;
        const int c = kk * 4 + l4;
        bfr[nt] = *(const f16x8*)&sB[row * 64 + ((c ^ (row & 7)) << 3)];
      }
#pragma unroll
      for (int mt = 0; mt < 4; ++mt)
#pragma unroll
        for (int nt = 0; nt < 4; ++nt)
          acc[mt][nt] = __builtin_amdgcn_mfma_f32_16x16x32_f16(af[mt], bfr[nt], acc[mt][nt], 0, 0, 0);
    }
  }

  if constexpr (EPI == 6) {
    const int head = (int)(bn0 >> 6) + wn;
#pragma unroll
    for (int mt = 0; mt < 4; ++mt)
#pragma unroll
      for (int r = 0; r < 4; ++r) {
        float bv = -1e30f, mv = 1e30f;
        int bi = 127, mi = 127;
#pragma unroll
        for (int nt = 0; nt < 4; ++nt) {
          const float v = acc[mt][nt][r];
          const int idx = nt * 16 + l15;
          if (v > bv) { bv = v; bi = idx; }
          if (v < mv) { mv = v; mi = idx; }
        }
#pragma unroll
        for (int mk = 1; mk < 16; mk <<= 1) {
          const float ov = __shfl_xor(bv, mk); const int oi = __shfl_xor(bi, mk);
          if (ov > bv || (ov == bv && oi < bi)) { bv = ov; bi = oi; }
          const float ou = __shfl_xor(mv, mk); const int ui = __shfl_xor(mi, mk);
          if (ou < mv || (ou == mv && ui < mi)) { mv = ou; mi = ui; }
        }
        if (l15 == 0) {
          const int bucket = (bv >= -mv) ? bi : 64 + mi;
          const long grow = bm0 + wm * 64 + mt * 16 + l4 * 4 + r;
          const int bb = (int)(grow >> 12), tt = (int)(grow & 4095);
          ibuf[((long)bb * 8 + head) * 4096 + tt] = bucket;
        }
      }
    return;
  }

  if constexpr (EPI == 5) {
    // qkv sorted scatter: wave col-span = one (head, qk/v) slice of 64 dims.
    const int hcol = (int)(bn0 >> 6) + wn;     // 0..15
    const int is_v = hcol >> 3, h = hcol & 7;
    f16* base = is_v ? outh2 : outh;
#pragma unroll
    for (int mt = 0; mt < 4; ++mt)
#pragma unroll
      for (int r = 0; r < 4; ++r) {
        const long grow = bm0 + wm * 64 + mt * 16 + l4 * 4 + r;
        const int bb = (int)(grow >> 12), tt = (int)(grow & 4095);
        const long bhb = (long)bb * 8 + h;
        const int pos = ibuf[bhb * 4096 + tt];
        f16* dst = base + (bhb * 4096 + pos) * 64;
#pragma unroll
        for (int nt = 0; nt < 4; ++nt)
          dst[nt * 16 + l15] = (f16)acc[mt][nt][r];
      }
    return;
  }

#pragma unroll
  for (int mt = 0; mt < 4; ++mt)
#pragma unroll
    for (int nt = 0; nt < 4; ++nt)
#pragma unroll
      for (int r = 0; r < 4; ++r) {
        const long grow = bm0 + wm * 64 + mt * 16 + l4 * 4 + r;
        const long gcol = bn0 + wn * 64 + nt * 16 + l15;
        const long idx  = grow * (long)N + gcol;
        const float c = acc[mt][nt][r];
        if constexpr (EPI == 2) {
          outf[idx] = c + bias[gcol] + add1[idx];
        } else if constexpr (EPI == 3) {
          outh[idx] = (f16)fmaxf(c + bias[gcol], 0.f);
        } else if constexpr (EPI == 4) {
          outf[idx] = 0.5f * (c + bias[gcol] + add1[idx] + add2[idx]);
        }
      }
}

// ---------------------------------------------------------------------------
// LayerNorm over D=512, one wave per row. split: writes [hi | (y-hi)*64].
// ---------------------------------------------------------------------------
__global__ __launch_bounds__(256)
void ln_kernel(const float* __restrict__ in, const float* __restrict__ gam,
               const float* __restrict__ bet, f16* __restrict__ out,
               int ldo, int split)
{
  const long row = (long)blockIdx.x * 4 + (threadIdx.x >> 6);
  const int lane = threadIdx.x & 63;
  const float4* p = (const float4*)(in + row * 512);
  const float4 a = p[lane * 2], b = p[lane * 2 + 1];
  float xv[8] = {a.x, a.y, a.z, a.w, b.x, b.y, b.z, b.w};
  float s = 0.f;
#pragma unroll
  for (int i = 0; i < 8; ++i) s += xv[i];
#pragma unroll
  for (int m = 32; m; m >>= 1) s += __shfl_xor(s, m);
  const float mean = s * (1.f / 512.f);
  float vs = 0.f;
#pragma unroll
  for (int i = 0; i < 8; ++i) { const float d = xv[i] - mean; vs += d * d; }
#pragma unroll
  for (int m = 32; m; m >>= 1) vs += __shfl_xor(vs, m);
  const float rstd = 1.f / sqrtf(vs * (1.f / 512.f) + 1e-5f);
  const float4* gp = (const float4*)gam;
  const float4* bp = (const float4*)bet;
  const float4 g0 = gp[lane * 2], g1 = gp[lane * 2 + 1];
  const float4 b0 = bp[lane * 2], b1 = bp[lane * 2 + 1];
  const float gg[8] = {g0.x, g0.y, g0.z, g0.w, g1.x, g1.y, g1.z, g1.w};
  const float bb[8] = {b0.x, b0.y, b0.z, b0.w, b1.x, b1.y, b1.z, b1.w};
  f16x8 vh, vl;
#pragma unroll
  for (int i = 0; i < 8; ++i) {
    const float y = (xv[i] - mean) * rstd * gg[i] + bb[i];
    const f16 hi = (f16)y;
    vh[i] = hi;
    vl[i] = (f16)((y - (float)hi) * 64.f);
  }
  f16* o = out + row * ldo + lane * 8;
  *(f16x8*)o = vh;
  if (split) *(f16x8*)(o + 512) = vl;
}

// ---------------------------------------------------------------------------
__global__ __launch_bounds__(256)
void transpose_f16(const float* __restrict__ src, f16* __restrict__ dst, int K, int N)
{
  __shared__ float tile[32][33];
  const int tx = threadIdx.x & 31, ty = threadIdx.x >> 5;
  const long k0 = (long)blockIdx.y * 32, n0 = (long)blockIdx.x * 32;
#pragma unroll
  for (int i = 0; i < 4; ++i)
    tile[ty + i * 8][tx] = src[(k0 + ty + i * 8) * N + n0 + tx];
  __syncthreads();
#pragma unroll
  for (int i = 0; i < 4; ++i)
    dst[(n0 + ty + i * 8) * K + k0 + tx] = (f16)tile[tx][ty + i * 8];
}

// ---------------------------------------------------------------------------
// Bucket-GEMM B rows: [Wr_hi*64 | Wr_hi | Wr_lo*64]  (x64 scale, argmax-inv.)
// ---------------------------------------------------------------------------
__global__ __launch_bounds__(256)
void whash_kernel(const float* __restrict__ wqk, const float* __restrict__ rot,
                  f16* __restrict__ bth)
{
  const int kk = blockIdx.x;
  const int n  = blockIdx.y * 256 + threadIdx.x;
  const int h = n >> 6, i = n & 63;
  float s = 0.f;
  for (int d = 0; d < 64; ++d)
    s += wqk[kk * 512 + h * 64 + d] * rot[d * 64 + i];
  const f16 whi = (f16)s;
  const float whif = (float)whi;
  bth[(long)n * 1536 + kk]        = (f16)(whif * 64.f);
  bth[(long)n * 1536 + 512 + kk]  = whi;
  bth[(long)n * 1536 + 1024 + kk] = (f16)((s - whif) * 64.f);
}

// ---------------------------------------------------------------------------
// Stable counting sort by (bucket, t) per bh. Writes sticker AND undo.
// ---------------------------------------------------------------------------
__global__ __launch_bounds__(256)
void sort_kernel(const int* __restrict__ buckets, int* __restrict__ sticker,
                 int* __restrict__ undo)
{
  __shared__ int bkt[4096];
  __shared__ unsigned int cnts[64][128];
  __shared__ unsigned char rnk[4096];
  __shared__ int tot[128];
  __shared__ int base[128];
  const int bh = blockIdx.x;
  const int tid = threadIdx.x;
  const int lane = tid & 63, wv = tid >> 6;

  for (int i = tid; i < 4096; i += 256) bkt[i] = buckets[(long)bh * 4096 + i] & 127;
  for (int i = tid; i < 64 * 128; i += 256) ((unsigned int*)cnts)[i] = 0u;
  __syncthreads();

  for (int it = 0; it < 16; ++it) {
    const int c = wv * 16 + it;
    const int t = c * 64 + lane;
    const int b = bkt[t];
    unsigned long long m = ~0ull;
#pragma unroll
    for (int k = 0; k < 7; ++k) {
      const bool bit = (b >> k) & 1;
      const unsigned long long bal = __ballot(bit);
      m &= bit ? bal : ~bal;
    }
    const int rk = (int)__popcll(m & ((1ull << lane) - 1ull));
    rnk[t] = (unsigned char)rk;
    if (rk == 0) cnts[c][b] = (unsigned int)__popcll(m);
  }
  __syncthreads();

  if (tid < 128) {
    unsigned int run = 0;
    for (int c = 0; c < 64; ++c) {
      const unsigned int x = cnts[c][tid];
      cnts[c][tid] = run;
      run += x;
    }
    tot[tid] = (int)run;
  }
  __syncthreads();
  if (tid == 0) {
    int run = 0;
    for (int b = 0; b < 128; ++b) { base[b] = run; run += tot[b]; }
  }
  __syncthreads();

  for (int it = 0; it < 16; ++it) {
    const int c = wv * 16 + it;
    const int t = c * 64 + lane;
    const int b = bkt[t];
    const int pos = base[b] + (int)cnts[c][b] + (int)rnk[t];
    sticker[(long)bh * 4096 + pos] = t;
    undo[(long)bh * 4096 + t] = pos;
  }
}

// ---------------------------------------------------------------------------
// LSH attention on SORTED data. Block = 256 thr / 4 waves / 4 chunks.
// Window = 160 rows [cg*128-32, cg*128+128). Wave w: queries rows 32+w*32..,
// keys rows w*32..w*32+64. gsqk/gsv: [bh][4096][64] f16.
// ---------------------------------------------------------------------------
__global__ __launch_bounds__(256)
void attn2_kernel(const f16* __restrict__ gqk, const f16* __restrict__ gv,
                  const int* __restrict__ sticker, f16* __restrict__ o)
{
  __shared__ __align__(16) f16 sqk[160 * 64];     // granule-XOR swizzled
  __shared__ __align__(16) f16 sVT[64 * 168];     // [d][key 0..159], pad 168
  __shared__ __align__(16) f16 sP[4][32 * 72];
  __shared__ float rnorm[160];
  __shared__ int st[128];

  const int tid = threadIdx.x, lane = tid & 63, w = tid >> 6;
  const int cg = blockIdx.x, bh = blockIdx.y;
  const int b = bh >> 3, h = bh & 7;
  const int p0 = cg * 128 - 32;
  const int l15 = lane & 15, l4 = lane >> 4;

  // stage sqk window (linear LDS dest; source granule pre-swizzled)
  const f16* gq = gqk + (long)bh * 4096 * 64;
#pragma unroll
  for (int it = 0; it < 5; ++it) {
    const int idx = it * 256 + tid;
    const int row = idx >> 3, g = idx & 7;
    const int gsrc = g ^ (row & 7);
    gload16(gq + (long)((p0 + row) & 4095) * 64 + gsrc * 8, &sqk[idx * 8]);
  }
  if (tid < 128) st[tid] = sticker[(long)bh * 4096 + cg * 128 + tid] & 4095;

  // V^T: wave w loads rows w*40..w*40+40 coalesced, writes transposed
  const f16* gvb = gv + (long)bh * 4096 * 64;
  f16x8 va[5];
#pragma unroll
  for (int i = 0; i < 5; ++i) {
    const int row = w * 40 + i * 8 + (lane >> 3);
    va[i] = *(const f16x8*)&gvb[(long)((p0 + row) & 4095) * 64 + (lane & 7) * 8];
  }
#pragma unroll
  for (int i = 0; i < 5; ++i) {
    const int row = w * 40 + i * 8 + (lane >> 3);
    const int d0 = (lane & 7) * 8;
#pragma unroll
    for (int e = 0; e < 8; ++e) sVT[(d0 + e) * 168 + row] = va[i][e];
  }
  __syncthreads();

  // inverse key norms (from staged f16 qk)
  if (tid < 160) {
    float s = 0.f;
#pragma unroll
    for (int g = 0; g < 8; ++g) {
      const f16x8 v = *(const f16x8*)&sqk[tid * 64 + ((g ^ (tid & 7)) << 3)];
#pragma unroll
      for (int e = 0; e < 8; ++e) { const float f = (float)v[e]; s += f * f; }
    }
    rnorm[tid] = 1.f / fmaxf(sqrtf(s), 1e-12f);
  }
  __syncthreads();

  // QK^T (raw x raw)
  f32x4 acc[2][4];
#pragma unroll
  for (int i = 0; i < 2; ++i)
#pragma unroll
    for (int j = 0; j < 4; ++j) acc[i][j] = f32x4{0.f, 0.f, 0.f, 0.f};

#pragma unroll
  for (int kk = 0; kk < 2; ++kk) {
    f16x8 aq[2], bk[4];
#pragma unroll
    for (int mt = 0; mt < 2; ++mt) {
      const int row = 32 + w * 32 + mt * 16 + l15;
      const int g = kk * 4 + l4;
      aq[mt] = *(const f16x8*)&sqk[row * 64 + ((g ^ (row & 7)) << 3)];
    }
#pragma unroll
    for (int nt = 0; nt < 4; ++nt) {
      const int row = w * 32 + nt * 16 + l15;
      const int g = kk * 4 + l4;
      bk[nt] = *(const f16x8*)&sqk[row * 64 + ((g ^ (row & 7)) << 3)];
    }
#pragma unroll
    for (int mt = 0; mt < 2; ++mt)
#pragma unroll
      for (int nt = 0; nt < 4; ++nt)
        acc[mt][nt] = __builtin_amdgcn_mfma_f32_16x16x32_f16(aq[mt], bk[nt], acc[mt][nt], 0, 0, 0);
  }

  // key scale factors (column scaling by 1/||k||)
  float rn[4];
#pragma unroll
  for (int nt = 0; nt < 4; ++nt) rn[nt] = rnorm[w * 32 + nt * 16 + l15];

  float pinv[2][4];
#pragma unroll
  for (int mt = 0; mt < 2; ++mt)
#pragma unroll
    for (int r = 0; r < 4; ++r) {
      const int row_i = mt * 16 + l4 * 4 + r;        // query idx 0..31
      float mx = -1e30f;
#pragma unroll
      for (int nt = 0; nt < 4; ++nt) {
        float v = acc[mt][nt][r] * 0.125f * rn[nt];
        if (nt * 16 + l15 == row_i + 32) v = -5e4f;  // self (key = query+32)
        acc[mt][nt][r] = v;
        mx = fmaxf(mx, v);
      }
#pragma unroll
      for (int m = 8; m; m >>= 1) mx = fmaxf(mx, __shfl_xor(mx, m));
      float ssum = 0.f;
#pragma unroll
      for (int nt = 0; nt < 4; ++nt) {
        const float pe = expf(acc[mt][nt][r] - mx);
        ssum += pe;
        sP[w][row_i * 72 + nt * 16 + l15] = (f16)pe;
      }
#pragma unroll
      for (int m = 8; m; m >>= 1) ssum += __shfl_xor(ssum, m);
      pinv[mt][r] = 1.f / ssum;
    }

  // PV
  f32x4 pacc[2][4];
#pragma unroll
  for (int i = 0; i < 2; ++i)
#pragma unroll
    for (int j = 0; j < 4; ++j) pacc[i][j] = f32x4{0.f, 0.f, 0.f, 0.f};

#pragma unroll
  for (int kk = 0; kk < 2; ++kk) {
    f16x8 ap[2], bv[4];
#pragma unroll
    for (int mt = 0; mt < 2; ++mt)
      ap[mt] = *(const f16x8*)&sP[w][(mt * 16 + l15) * 72 + kk * 32 + l4 * 8];
#pragma unroll
    for (int nt = 0; nt < 4; ++nt)
      bv[nt] = *(const f16x8*)&sVT[(nt * 16 + l15) * 168 + w * 32 + kk * 32 + l4 * 8];
#pragma unroll
    for (int mt = 0; mt < 2; ++mt)
#pragma unroll
      for (int nt = 0; nt < 4; ++nt)
        pacc[mt][nt] = __builtin_amdgcn_mfma_f32_16x16x32_f16(ap[mt], bv[nt], pacc[mt][nt], 0, 0, 0);
  }

  const long ob = (long)b * 4096 * 512 + h * 64;
#pragma unroll
  for (int mt = 0; mt < 2; ++mt)
#pragma unroll
    for (int r = 0; r < 4; ++r) {
      const int row_i = mt * 16 + l4 * 4 + r;
      const long t = st[w * 32 + row_i];
      const float sc = pinv[mt][r];
#pragma unroll
      for (int nt = 0; nt < 4; ++nt)
        o[ob + t * 512 + nt * 16 + l15] = (f16)(pacc[mt][nt][r] * sc);
    }
}

// ---------------------------------------------------------------------------
extern "C" void kernel_launch(void* const* d_in, const int* in_sizes, int n_in,
                              void* d_out, int out_size, void* d_ws, size_t ws_size,
                              hipStream_t stream)
{
  const float* x     = (const float*)d_in[0];
  const float* w_qk  = (const float*)d_in[1];
  const float* w_v   = (const float*)d_in[2];
  const float* w_out = (const float*)d_in[3];
  const float* b_out = (const float*)d_in[4];
  const float* ln1g  = (const float*)d_in[5];
  const float* ln1b  = (const float*)d_in[6];
  const float* w_ff1 = (const float*)d_in[7];
  const float* b_ff1 = (const float*)d_in[8];
  const float* w_ff2 = (const float*)d_in[9];
  const float* b_ff2 = (const float*)d_in[10];
  const float* ln2g  = (const float*)d_in[11];
  const float* ln2b  = (const float*)d_in[12];
  const float* rot   = (const float*)d_in[13];
  float* out = (float*)d_out;   // also y1 (read-before-write in EPI4)

  char* ws = (char*)d_ws;
  // [0,64M):    hsplit f16 [32768][1024]  -> later o[0,32M) + h2[32M,64M)
  // [64M,128M): gsqk [64][4096][64] + gsv [64][4096][64] -> later abuf [16384][2048]
  // [128M,~138M): weights + buckets/undo + sticker
  f16* hsplit = (f16*)ws;
  f16* o_buf  = (f16*)ws;
  f16* h2     = (f16*)(ws + 33554432);
  f16* gsqk   = (f16*)(ws + 67108864);
  f16* gsv    = (f16*)(ws + 100663296);
  f16* abuf   = (f16*)(ws + 67108864);          // FFN mid, after attn
  char* W0 = ws + 134217728;
  f16* wqkvT = (f16*)W0;                        // [1024][512]
  f16* woutT = (f16*)(W0 + 1048576);            // [512][512]
  f16* wff1T = (f16*)(W0 + 1572864);            // [2048][512]
  f16* wff2T = (f16*)(W0 + 3670016);            // [512][2048]
  f16* bth   = (f16*)(W0 + 5767168);            // [512][1536]
  int* buckets = (int*)(W0 + 7340032);          // [64][4096]; undo aliases after sort reads
  int* undo    = (int*)(W0 + 7340032);
  int* sticker = (int*)(W0 + 8388608);          // [64][4096]

  const dim3 b256(256);
  transpose_f16<<<dim3(16, 16), b256, 0, stream>>>(w_qk,  wqkvT,             512, 512);
  transpose_f16<<<dim3(16, 16), b256, 0, stream>>>(w_v,   wqkvT + 512 * 512, 512, 512);
  transpose_f16<<<dim3(16, 16), b256, 0, stream>>>(w_out, woutT,             512, 512);
  transpose_f16<<<dim3(64, 16), b256, 0, stream>>>(w_ff1, wff1T,             512, 2048);
  transpose_f16<<<dim3(16, 64), b256, 0, stream>>>(w_ff2, wff2T,             2048, 512);
  whash_kernel<<<dim3(512, 2), b256, 0, stream>>>(w_qk, rot, bth);
  // LN1: [hhi | hlo*64], row stride 1024
  ln_kernel<<<dim3(8192), b256, 0, stream>>>(x, ln1g, ln1b, hsplit, 1024, 1);
  // buckets via 3-term split GEMM (K=1536, A wraps) + fused argmax
  gemm_bt<6, 1><<<dim3(4, 256), b256, 0, stream>>>(hsplit, 1024, bth, 1536, 1536, 512,
      nullptr, nullptr, nullptr, nullptr, nullptr, nullptr, buckets);
  sort_kernel<<<dim3(64), b256, 0, stream>>>(buckets, sticker, undo);
  // qkv GEMM with sorted scatter epilogue
  gemm_bt<5, 0><<<dim3(8, 256), b256, 0, stream>>>(hsplit, 1024, wqkvT, 512, 512, 1024,
      nullptr, gsqk, gsv, nullptr, nullptr, nullptr, undo);
  attn2_kernel<<<dim3(32, 64), b256, 0, stream>>>(gsqk, gsv, sticker, o_buf);
  // y1 (in d_out) = x + o @ w_out + b_out
  gemm_bt<2, 0><<<dim3(4, 256), b256, 0, stream>>>(o_buf, 512, woutT, 512, 512, 512,
      out, nullptr, nullptr, b_out, x, nullptr, nullptr);
  ln_kernel<<<dim3(8192), b256, 0, stream>>>(out, ln2g, ln2b, h2, 512, 0);
  // FFN in 2 row-chunks of 16384
  for (int c = 0; c < 2; ++c) {
    const long roff = (long)c * 16384;
    gemm_bt<3, 0><<<dim3(16, 128), b256, 0, stream>>>(h2 + roff * 512, 512, wff1T, 512, 512, 2048,
        nullptr, abuf, nullptr, b_ff1, nullptr, nullptr, nullptr);
    gemm_bt<4, 0><<<dim3(4, 128), b256, 0, stream>>>(abuf, 2048, wff2T, 2048, 2048, 512,
        out + roff * 512, nullptr, nullptr, b_ff2, x + roff * 512, out + roff * 512, nullptr);
  }
}

// Round 4
// 578.480 us; speedup vs baseline: 1.3907x; 1.0190x over previous
//
#include <hip/hip_runtime.h>
#include <stdint.h>

typedef _Float16 f16;
typedef _Float16 f16x8 __attribute__((ext_vector_type(8)));
typedef float    f32x4 __attribute__((ext_vector_type(4)));

#define FIX_CAP 32768

__device__ __forceinline__ void gload16(const void* g, void* l) {
  __builtin_amdgcn_global_load_lds(
      (__attribute__((address_space(1))) void*)g,
      (__attribute__((address_space(3))) void*)l, 16, 0, 0);
}

// ---------------------------------------------------------------------------
// GEMM: C[M][N] = A[M][lda] * Bt[N][ldb]^T   (f16 inputs, fp32 accum)
// 128x128 tile, BK=64, 4 waves (2x2), mfma_f32_16x16x32_f16.
// EPI: 2 = fp32 c+bias+add1 | 3 = f16 relu(c+bias) |
//      4 = fp32 0.5*(c+bias+add1+add2) | 7 = f16 head-major qk/v write
// ---------------------------------------------------------------------------
template<int EPI>
__global__ __launch_bounds__(256)
void gemm_bt(const f16* __restrict__ A, int lda,
             const f16* __restrict__ Bt, int ldb,
             int K, int N,
             float* __restrict__ outf, f16* __restrict__ outh,
             f16* __restrict__ outh2,
             const float* __restrict__ bias,
             const float* __restrict__ add1,
             const float* __restrict__ add2)
{
  __shared__ __align__(16) f16 sA[128 * 64];
  __shared__ __align__(16) f16 sB[128 * 64];
  const int tid  = threadIdx.x;
  const int lane = tid & 63;
  const int wv   = tid >> 6;
  const int wm   = wv >> 1, wn = wv & 1;
  const int l15  = lane & 15, l4 = lane >> 4;
  const long bm0 = (long)blockIdx.y * 128;
  const long bn0 = (long)blockIdx.x * 128;

  f32x4 acc[4][4];
#pragma unroll
  for (int i = 0; i < 4; ++i)
#pragma unroll
    for (int j = 0; j < 4; ++j) acc[i][j] = f32x4{0.f, 0.f, 0.f, 0.f};

  const int rs = tid >> 3;
  const int cs = tid & 7;
  const int cg = cs ^ (rs & 7);

  const int nkt = K >> 6;
  for (int kt = 0; kt < nkt; ++kt) {
    __syncthreads();
    const long ka = (long)kt * 64 + cg * 8;
#pragma unroll
    for (int rd = 0; rd < 4; ++rd) {
      const int row = rs + rd * 32;
      gload16(A + (bm0 + row) * lda + ka, &sA[row * 64 + cs * 8]);
    }
#pragma unroll
    for (int rd = 0; rd < 4; ++rd) {
      const int row = rs + rd * 32;
      gload16(Bt + (bn0 + row) * ldb + ka, &sB[row * 64 + cs * 8]);
    }
    __syncthreads();
#pragma unroll
    for (int kk = 0; kk < 2; ++kk) {
      f16x8 af[4], bfr[4];
#pragma unroll
      for (int mt = 0; mt < 4; ++mt) {
        const int row = wm * 64 + mt * 16 + l15;
        const int c = kk * 4 + l4;
        af[mt] = *(const f16x8*)&sA[row * 64 + ((c ^ (row & 7)) << 3)];
      }
#pragma unroll
      for (int nt = 0; nt < 4; ++nt) {
        const int row = wn * 64 + nt * 16 + l15;
        const int c = kk * 4 + l4;
        bfr[nt] = *(const f16x8*)&sB[row * 64 + ((c ^ (row & 7)) << 3)];
      }
#pragma unroll
      for (int mt = 0; mt < 4; ++mt)
#pragma unroll
        for (int nt = 0; nt < 4; ++nt)
          acc[mt][nt] = __builtin_amdgcn_mfma_f32_16x16x32_f16(af[mt], bfr[nt], acc[mt][nt], 0, 0, 0);
    }
  }

  if constexpr (EPI == 7) {
    // head-major qk/v: wave col-span = one (head, qk/v) slice of 64 dims.
    const int hcol = (int)(bn0 >> 6) + wn;     // 0..15
    const int is_v = hcol >> 3, h = hcol & 7;
    f16* base = is_v ? outh2 : outh;
#pragma unroll
    for (int mt = 0; mt < 4; ++mt)
#pragma unroll
      for (int r = 0; r < 4; ++r) {
        const long grow = bm0 + wm * 64 + mt * 16 + l4 * 4 + r;
        const int bb = (int)(grow >> 12), tt = (int)(grow & 4095);
        f16* dst = base + (((long)bb * 8 + h) * 4096 + tt) * 64;
#pragma unroll
        for (int nt = 0; nt < 4; ++nt)
          dst[nt * 16 + l15] = (f16)acc[mt][nt][r];
      }
    return;
  }

#pragma unroll
  for (int mt = 0; mt < 4; ++mt)
#pragma unroll
    for (int nt = 0; nt < 4; ++nt)
#pragma unroll
      for (int r = 0; r < 4; ++r) {
        const long grow = bm0 + wm * 64 + mt * 16 + l4 * 4 + r;
        const long gcol = bn0 + wn * 64 + nt * 16 + l15;
        const long idx  = grow * (long)N + gcol;
        const float c = acc[mt][nt][r];
        if constexpr (EPI == 2) {
          outf[idx] = c + bias[gcol] + add1[idx];
        } else if constexpr (EPI == 3) {
          outh[idx] = (f16)fmaxf(c + bias[gcol], 0.f);
        } else if constexpr (EPI == 4) {
          outf[idx] = 0.5f * (c + bias[gcol] + add1[idx] + add2[idx]);
        }
      }
}

// ---------------------------------------------------------------------------
// LayerNorm over D=512, one wave per row. split: writes [hi | (y-hi)*64].
// ---------------------------------------------------------------------------
__global__ __launch_bounds__(256)
void ln_kernel(const float* __restrict__ in, const float* __restrict__ gam,
               const float* __restrict__ bet, f16* __restrict__ out,
               int ldo, int split)
{
  const long row = (long)blockIdx.x * 4 + (threadIdx.x >> 6);
  const int lane = threadIdx.x & 63;
  const float4* p = (const float4*)(in + row * 512);
  const float4 a = p[lane * 2], b = p[lane * 2 + 1];
  float xv[8] = {a.x, a.y, a.z, a.w, b.x, b.y, b.z, b.w};
  float s = 0.f;
#pragma unroll
  for (int i = 0; i < 8; ++i) s += xv[i];
#pragma unroll
  for (int m = 32; m; m >>= 1) s += __shfl_xor(s, m);
  const float mean = s * (1.f / 512.f);
  float vs = 0.f;
#pragma unroll
  for (int i = 0; i < 8; ++i) { const float d = xv[i] - mean; vs += d * d; }
#pragma unroll
  for (int m = 32; m; m >>= 1) vs += __shfl_xor(vs, m);
  const float rstd = 1.f / sqrtf(vs * (1.f / 512.f) + 1e-5f);
  const float4* gp = (const float4*)gam;
  const float4* bp = (const float4*)bet;
  const float4 g0 = gp[lane * 2], g1 = gp[lane * 2 + 1];
  const float4 b0 = bp[lane * 2], b1 = bp[lane * 2 + 1];
  const float gg[8] = {g0.x, g0.y, g0.z, g0.w, g1.x, g1.y, g1.z, g1.w};
  const float bb[8] = {b0.x, b0.y, b0.z, b0.w, b1.x, b1.y, b1.z, b1.w};
  f16x8 vh, vl;
#pragma unroll
  for (int i = 0; i < 8; ++i) {
    const float y = (xv[i] - mean) * rstd * gg[i] + bb[i];
    const f16 hi = (f16)y;
    vh[i] = hi;
    vl[i] = (f16)((y - (float)hi) * 64.f);
  }
  f16* o = out + row * ldo + lane * 8;
  *(f16x8*)o = vh;
  if (split) *(f16x8*)(o + 512) = vl;
}

// ---------------------------------------------------------------------------
__global__ __launch_bounds__(256)
void transpose_f16(const float* __restrict__ src, f16* __restrict__ dst, int K, int N)
{
  __shared__ float tile[32][33];
  const int tx = threadIdx.x & 31, ty = threadIdx.x >> 5;
  const long k0 = (long)blockIdx.y * 32, n0 = (long)blockIdx.x * 32;
#pragma unroll
  for (int i = 0; i < 4; ++i)
    tile[ty + i * 8][tx] = src[(k0 + ty + i * 8) * N + n0 + tx];
  __syncthreads();
#pragma unroll
  for (int i = 0; i < 4; ++i)
    dst[(n0 + ty + i * 8) * K + k0 + tx] = (f16)tile[tx][ty + i * 8];
}

// ---------------------------------------------------------------------------
// WrT[n][k] = sum_d w_qk[k][h*64+d]*rot[d][i]  (n = h*64+i), fp32 (for fixup).
// Also zeroes the fixup counter.
// ---------------------------------------------------------------------------
__global__ __launch_bounds__(256)
void whash_f32(const float* __restrict__ wqk, const float* __restrict__ rot,
               float* __restrict__ WrT, int* __restrict__ ctr)
{
  if (blockIdx.x == 0 && blockIdx.y == 0 && threadIdx.x == 0) ctr[0] = 0;
  const int kk = blockIdx.x;                     // 0..511
  const int n  = blockIdx.y * 256 + threadIdx.x; // 0..511
  const int h = n >> 6, i = n & 63;
  float s = 0.f;
  for (int d = 0; d < 64; ++d)
    s += wqk[kk * 512 + h * 64 + d] * rot[d * 64 + i];
  WrT[(long)n * 512 + kk] = s;
}

// ---------------------------------------------------------------------------
// rhash: r[t][i] = qk[t][:] . rot[:][i] per (bh, 128-token tile) via MFMA
// (K=64). Per row: bucket = argmax over [r, -r]; flag near-ties with top-3
// candidates per side for exact fixup.
// ---------------------------------------------------------------------------
__global__ __launch_bounds__(256)
void rhash_kernel(const f16* __restrict__ gqk, const float* __restrict__ rot,
                  int* __restrict__ buckets, int* __restrict__ ctr,
                  int4* __restrict__ list)
{
  __shared__ __align__(16) f16 sA[128 * 64];
  __shared__ __align__(16) f16 rotT[64 * 64];
  __shared__ float scores[128 * 65];

  const int tid = threadIdx.x, lane = tid & 63, w = tid >> 6;
  const int bh = blockIdx.x >> 5, tb = blockIdx.x & 31;
  const int t0 = tb * 128;
  const int l15 = lane & 15, l4 = lane >> 4;

  // stage qk tile (source-swizzled, linear LDS dest)
  const f16* gqb = gqk + ((long)bh * 4096 + t0) * 64;
#pragma unroll
  for (int it = 0; it < 4; ++it) {
    const int idx = it * 256 + tid;
    const int row = idx >> 3, ch = idx & 7;
    const int gsrc = ch ^ (row & 7);
    gload16(gqb + (long)row * 64 + gsrc * 8, &sA[idx * 8]);
  }
  // stage rot transposed to f16 [i][d], same XOR layout
#pragma unroll
  for (int e = 0; e < 16; ++e) {
    const int idx = e * 256 + tid;       // d*64 + i
    const int d = idx >> 6, i = idx & 63;
    const int g = d >> 3, el = d & 7;
    rotT[i * 64 + ((g ^ (i & 7)) << 3) + el] = (f16)rot[idx];
  }
  __syncthreads();

  f32x4 acc[2][4];
#pragma unroll
  for (int i = 0; i < 2; ++i)
#pragma unroll
    for (int j = 0; j < 4; ++j) acc[i][j] = f32x4{0.f, 0.f, 0.f, 0.f};

#pragma unroll
  for (int kk = 0; kk < 2; ++kk) {
    f16x8 aq[2], br[4];
#pragma unroll
    for (int mt = 0; mt < 2; ++mt) {
      const int row = w * 32 + mt * 16 + l15;
      const int g = kk * 4 + l4;
      aq[mt] = *(const f16x8*)&sA[row * 64 + ((g ^ (row & 7)) << 3)];
    }
#pragma unroll
    for (int nt = 0; nt < 4; ++nt) {
      const int row = nt * 16 + l15;
      const int g = kk * 4 + l4;
      br[nt] = *(const f16x8*)&rotT[row * 64 + ((g ^ (row & 7)) << 3)];
    }
#pragma unroll
    for (int mt = 0; mt < 2; ++mt)
#pragma unroll
      for (int nt = 0; nt < 4; ++nt)
        acc[mt][nt] = __builtin_amdgcn_mfma_f32_16x16x32_f16(aq[mt], br[nt], acc[mt][nt], 0, 0, 0);
  }

#pragma unroll
  for (int mt = 0; mt < 2; ++mt)
#pragma unroll
    for (int r = 0; r < 4; ++r) {
      const int row = w * 32 + mt * 16 + l4 * 4 + r;
#pragma unroll
      for (int nt = 0; nt < 4; ++nt)
        scores[row * 65 + nt * 16 + l15] = acc[mt][nt][r];
    }
  __syncthreads();

  if (tid < 128) {
    const float* sr = &scores[tid * 65];
    float a0 = -1e30f, a1 = -1e30f, a2 = -1e30f;
    float m0 = 1e30f,  m1 = 1e30f,  m2 = 1e30f;
    int i0 = 0, i1 = 0, i2 = 0, j0 = 0, j1 = 0, j2 = 0;
    float sumsq = 0.f;
    for (int i = 0; i < 64; ++i) {
      const float v = sr[i];
      sumsq += v * v;
      if (v > a0)      { a2 = a1; i2 = i1; a1 = a0; i1 = i0; a0 = v; i0 = i; }
      else if (v > a1) { a2 = a1; i2 = i1; a1 = v; i1 = i; }
      else if (v > a2) { a2 = v; i2 = i; }
      if (v < m0)      { m2 = m1; j2 = j1; m1 = m0; j1 = j0; m0 = v; j0 = i; }
      else if (v < m1) { m2 = m1; j2 = j1; m1 = v; j1 = i; }
      else if (v < m2) { m2 = v; j2 = i; }
    }
    const float vA = a0, vB = -m0;
    int bucket; float second;
    if (vA >= vB) { bucket = i0;      second = fmaxf(a1, vB); }
    else          { bucket = 64 + j0; second = fmaxf(vA, -m1); }
    const int bht = bh * 4096 + t0 + tid;
    buckets[bht] = bucket;
    const float margin = fmaxf(vA, vB) - second;
    const float rms = sqrtf(sumsq * (1.f / 64.f));
    if (margin < 0.015f * rms) {
      const int idx = atomicAdd(ctr, 1);
      if (idx < FIX_CAP) {
        int4 e;
        e.x = bht;
        e.y = i0 | (i1 << 8) | (i2 << 16) | ((64 + j0) << 24);
        e.z = (64 + j1) | ((64 + j2) << 8);
        e.w = 0;
        list[idx] = e;
      }
    }
  }
}

// ---------------------------------------------------------------------------
// fixup: exact fp32 re-evaluation of the 6 candidate directions for flagged
// rows; one wave per item. h1 = hi + lo/64 (≈fp32), WrT fp32.
// ---------------------------------------------------------------------------
__global__ __launch_bounds__(256)
void fixup_kernel(const f16* __restrict__ hsplit, const float* __restrict__ WrT,
                  const int* __restrict__ ctr, const int4* __restrict__ list,
                  int* __restrict__ buckets)
{
  const int n = min(ctr[0], FIX_CAP);
  const int gw = (blockIdx.x * 256 + threadIdx.x) >> 6;
  const int nw = gridDim.x * 4;
  const int lane = threadIdx.x & 63;
  for (int it = gw; it < n; it += nw) {
    const int4 e = list[it];
    const int bht = e.x;
    const int h = (bht >> 12) & 7;
    const long hrow = (long)(bht >> 15) * 4096 + (bht & 4095);
    const f16* hp = hsplit + hrow * 1024 + lane * 8;
    const f16x8 hi = *(const f16x8*)hp;
    const f16x8 lo = *(const f16x8*)(hp + 512);
    float h1[8];
#pragma unroll
    for (int k = 0; k < 8; ++k) h1[k] = (float)hi[k] + (float)lo[k] * 0.015625f;
    const int cands[6] = { e.y & 127, (e.y >> 8) & 127, (e.y >> 16) & 127,
                           (e.y >> 24) & 127, e.z & 127, (e.z >> 8) & 127 };
    float best = -1e30f; int bi = 999;
#pragma unroll
    for (int c = 0; c < 6; ++c) {
      const int cc = cands[c];
      const float* wp = WrT + ((long)(h * 64 + (cc & 63))) * 512 + lane * 8;
      const float4 w0 = *(const float4*)wp;
      const float4 w1 = *(const float4*)(wp + 4);
      float s = h1[0] * w0.x + h1[1] * w0.y + h1[2] * w0.z + h1[3] * w0.w
              + h1[4] * w1.x + h1[5] * w1.y + h1[6] * w1.z + h1[7] * w1.w;
#pragma unroll
      for (int m = 32; m; m >>= 1) s += __shfl_xor(s, m);
      const float v = (cc >= 64) ? -s : s;
      if (v > best || (v == best && cc < bi)) { best = v; bi = cc; }
    }
    if (lane == 0) buckets[bht] = bi;
  }
}

// ---------------------------------------------------------------------------
// Stable counting sort by (bucket, t) per bh. sticker[pos] = original t.
// ---------------------------------------------------------------------------
__global__ __launch_bounds__(256)
void sort_kernel(const int* __restrict__ buckets, int* __restrict__ sticker)
{
  __shared__ int bkt[4096];
  __shared__ unsigned int cnts[64][128];
  __shared__ unsigned char rnk[4096];
  __shared__ int tot[128];
  __shared__ int base[128];
  const int bh = blockIdx.x;
  const int tid = threadIdx.x;
  const int lane = tid & 63, wv = tid >> 6;

  for (int i = tid; i < 4096; i += 256) bkt[i] = buckets[(long)bh * 4096 + i] & 127;
  for (int i = tid; i < 64 * 128; i += 256) ((unsigned int*)cnts)[i] = 0u;
  __syncthreads();

  for (int it = 0; it < 16; ++it) {
    const int c = wv * 16 + it;
    const int t = c * 64 + lane;
    const int b = bkt[t];
    unsigned long long m = ~0ull;
#pragma unroll
    for (int k = 0; k < 7; ++k) {
      const bool bit = (b >> k) & 1;
      const unsigned long long bal = __ballot(bit);
      m &= bit ? bal : ~bal;
    }
    const int rk = (int)__popcll(m & ((1ull << lane) - 1ull));
    rnk[t] = (unsigned char)rk;
    if (rk == 0) cnts[c][b] = (unsigned int)__popcll(m);
  }
  __syncthreads();

  if (tid < 128) {
    unsigned int run = 0;
    for (int c = 0; c < 64; ++c) {
      const unsigned int x = cnts[c][tid];
      cnts[c][tid] = run;
      run += x;
    }
    tot[tid] = (int)run;
  }
  __syncthreads();
  if (tid == 0) {
    int run = 0;
    for (int b = 0; b < 128; ++b) { base[b] = run; run += tot[b]; }
  }
  __syncthreads();

  for (int it = 0; it < 16; ++it) {
    const int c = wv * 16 + it;
    const int t = c * 64 + lane;
    const int b = bkt[t];
    const int pos = base[b] + (int)cnts[c][b] + (int)rnk[t];
    sticker[(long)bh * 4096 + pos] = t;
  }
}

// ---------------------------------------------------------------------------
// LSH attention, gather version. Block = 256 thr / 4 waves / 4 chunks.
// Window = sorted positions [cg*128-32, cg*128+128); rows gathered from
// head-major unsorted gqk/gv via sticker.
// ---------------------------------------------------------------------------
__global__ __launch_bounds__(256)
void attn2_kernel(const f16* __restrict__ gqk, const f16* __restrict__ gv,
                  const int* __restrict__ sticker, f16* __restrict__ o)
{
  __shared__ __align__(16) f16 sqk[160 * 64];     // granule-XOR swizzled
  __shared__ __align__(16) f16 sVT[64 * 168];     // [d][key 0..159]
  __shared__ __align__(16) f16 sP[4][32 * 72];
  __shared__ float rnorm[160];
  __shared__ int st[160];

  const int tid = threadIdx.x, lane = tid & 63, w = tid >> 6;
  const int cg = blockIdx.x, bh = blockIdx.y;
  const int b = bh >> 3, h = bh & 7;
  const int p0 = cg * 128 - 32;
  const int l15 = lane & 15, l4 = lane >> 4;

  if (tid < 160) st[tid] = sticker[(long)bh * 4096 + ((p0 + tid) & 4095)] & 4095;
  __syncthreads();

  const f16* gqb = gqk + (long)bh * 4096 * 64;
#pragma unroll
  for (int it = 0; it < 5; ++it) {
    const int idx = it * 256 + tid;
    const int row = idx >> 3, ch = idx & 7;
    const int gsrc = ch ^ (row & 7);
    gload16(gqb + (long)st[row] * 64 + gsrc * 8, &sqk[idx * 8]);
  }

  const f16* gvb = gv + (long)bh * 4096 * 64;
  f16x8 va[5];
#pragma unroll
  for (int i = 0; i < 5; ++i) {
    const int row = w * 40 + i * 8 + (lane >> 3);
    va[i] = *(const f16x8*)&gvb[(long)st[row] * 64 + (lane & 7) * 8];
  }
#pragma unroll
  for (int i = 0; i < 5; ++i) {
    const int row = w * 40 + i * 8 + (lane >> 3);
    const int d0 = (lane & 7) * 8;
#pragma unroll
    for (int e = 0; e < 8; ++e) sVT[(d0 + e) * 168 + row] = va[i][e];
  }
  __syncthreads();

  if (tid < 160) {
    float s = 0.f;
#pragma unroll
    for (int g = 0; g < 8; ++g) {
      const f16x8 v = *(const f16x8*)&sqk[tid * 64 + ((g ^ (tid & 7)) << 3)];
#pragma unroll
      for (int e = 0; e < 8; ++e) { const float f = (float)v[e]; s += f * f; }
    }
    rnorm[tid] = 1.f / fmaxf(sqrtf(s), 1e-12f);
  }
  __syncthreads();

  f32x4 acc[2][4];
#pragma unroll
  for (int i = 0; i < 2; ++i)
#pragma unroll
    for (int j = 0; j < 4; ++j) acc[i][j] = f32x4{0.f, 0.f, 0.f, 0.f};

#pragma unroll
  for (int kk = 0; kk < 2; ++kk) {
    f16x8 aq[2], bk[4];
#pragma unroll
    for (int mt = 0; mt < 2; ++mt) {
      const int row = 32 + w * 32 + mt * 16 + l15;
      const int g = kk * 4 + l4;
      aq[mt] = *(const f16x8*)&sqk[row * 64 + ((g ^ (row & 7)) << 3)];
    }
#pragma unroll
    for (int nt = 0; nt < 4; ++nt) {
      const int row = w * 32 + nt * 16 + l15;
      const int g = kk * 4 + l4;
      bk[nt] = *(const f16x8*)&sqk[row * 64 + ((g ^ (row & 7)) << 3)];
    }
#pragma unroll
    for (int mt = 0; mt < 2; ++mt)
#pragma unroll
      for (int nt = 0; nt < 4; ++nt)
        acc[mt][nt] = __builtin_amdgcn_mfma_f32_16x16x32_f16(aq[mt], bk[nt], acc[mt][nt], 0, 0, 0);
  }

  float rn[4];
#pragma unroll
  for (int nt = 0; nt < 4; ++nt) rn[nt] = rnorm[w * 32 + nt * 16 + l15];

  float pinv[2][4];
#pragma unroll
  for (int mt = 0; mt < 2; ++mt)
#pragma unroll
    for (int r = 0; r < 4; ++r) {
      const int row_i = mt * 16 + l4 * 4 + r;
      float mx = -1e30f;
#pragma unroll
      for (int nt = 0; nt < 4; ++nt) {
        float v = acc[mt][nt][r] * 0.125f * rn[nt];
        if (nt * 16 + l15 == row_i + 32) v = -5e4f;
        acc[mt][nt][r] = v;
        mx = fmaxf(mx, v);
      }
#pragma unroll
      for (int m = 8; m; m >>= 1) mx = fmaxf(mx, __shfl_xor(mx, m));
      float ssum = 0.f;
#pragma unroll
      for (int nt = 0; nt < 4; ++nt) {
        const float pe = expf(acc[mt][nt][r] - mx);
        ssum += pe;
        sP[w][row_i * 72 + nt * 16 + l15] = (f16)pe;
      }
#pragma unroll
      for (int m = 8; m; m >>= 1) ssum += __shfl_xor(ssum, m);
      pinv[mt][r] = 1.f / ssum;
    }
  __syncthreads();

  f32x4 pacc[2][4];
#pragma unroll
  for (int i = 0; i < 2; ++i)
#pragma unroll
    for (int j = 0; j < 4; ++j) pacc[i][j] = f32x4{0.f, 0.f, 0.f, 0.f};

#pragma unroll
  for (int kk = 0; kk < 2; ++kk) {
    f16x8 ap[2], bv[4];
#pragma unroll
    for (int mt = 0; mt < 2; ++mt)
      ap[mt] = *(const f16x8*)&sP[w][(mt * 16 + l15) * 72 + kk * 32 + l4 * 8];
#pragma unroll
    for (int nt = 0; nt < 4; ++nt)
      bv[nt] = *(const f16x8*)&sVT[(nt * 16 + l15) * 168 + w * 32 + kk * 32 + l4 * 8];
#pragma unroll
    for (int mt = 0; mt < 2; ++mt)
#pragma unroll
      for (int nt = 0; nt < 4; ++nt)
        pacc[mt][nt] = __builtin_amdgcn_mfma_f32_16x16x32_f16(ap[mt], bv[nt], pacc[mt][nt], 0, 0, 0);
  }

  const long ob = (long)b * 4096 * 512 + h * 64;
#pragma unroll
  for (int mt = 0; mt < 2; ++mt)
#pragma unroll
    for (int r = 0; r < 4; ++r) {
      const int row_i = mt * 16 + l4 * 4 + r;
      const long t = st[32 + w * 32 + row_i];
      const float sc = pinv[mt][r];
#pragma unroll
      for (int nt = 0; nt < 4; ++nt)
        o[ob + t * 512 + nt * 16 + l15] = (f16)(pacc[mt][nt][r] * sc);
    }
}

// ---------------------------------------------------------------------------
extern "C" void kernel_launch(void* const* d_in, const int* in_sizes, int n_in,
                              void* d_out, int out_size, void* d_ws, size_t ws_size,
                              hipStream_t stream)
{
  const float* x     = (const float*)d_in[0];
  const float* w_qk  = (const float*)d_in[1];
  const float* w_v   = (const float*)d_in[2];
  const float* w_out = (const float*)d_in[3];
  const float* b_out = (const float*)d_in[4];
  const float* ln1g  = (const float*)d_in[5];
  const float* ln1b  = (const float*)d_in[6];
  const float* w_ff1 = (const float*)d_in[7];
  const float* b_ff1 = (const float*)d_in[8];
  const float* w_ff2 = (const float*)d_in[9];
  const float* b_ff2 = (const float*)d_in[10];
  const float* ln2g  = (const float*)d_in[11];
  const float* ln2b  = (const float*)d_in[12];
  const float* rot   = (const float*)d_in[13];
  float* out = (float*)d_out;   // also y1 (read-before-write in EPI4)

  char* ws = (char*)d_ws;
  // [0,64M):    hsplit f16 [32768][1024]  (dead after fixup) -> o_buf[0,32M) + h2[32M,64M)
  // [64M,96M):  gqk [64][4096][64] f16    (dead after attn2) -> abuf [16384][2048]
  // [96M,128M): gv  [64][4096][64] f16
  // [128M,+9.4M): weights + WrT + buckets + sticker + ctr + list
  f16* hsplit = (f16*)ws;
  f16* o_buf  = (f16*)ws;
  f16* h2     = (f16*)(ws + 33554432);
  f16* gqk    = (f16*)(ws + 67108864);
  f16* gv     = (f16*)(ws + 100663296);
  f16* abuf   = (f16*)(ws + 67108864);
  char* W0 = ws + 134217728;
  f16* wqkvT = (f16*)W0;                        // [1024][512]
  f16* woutT = (f16*)(W0 + 1048576);            // [512][512]
  f16* wff1T = (f16*)(W0 + 1572864);            // [2048][512]
  f16* wff2T = (f16*)(W0 + 3670016);            // [512][2048]
  float* WrT = (float*)(W0 + 5767168);          // [512][512] fp32
  int* buckets = (int*)(W0 + 6815744);          // [64][4096]
  int* sticker = (int*)(W0 + 7864320);          // [64][4096]
  int* ctr     = (int*)(W0 + 8912896);
  int4* list   = (int4*)(W0 + 8912912);         // [32768]

  const dim3 b256(256);
  transpose_f16<<<dim3(16, 16), b256, 0, stream>>>(w_qk,  wqkvT,             512, 512);
  transpose_f16<<<dim3(16, 16), b256, 0, stream>>>(w_v,   wqkvT + 512 * 512, 512, 512);
  transpose_f16<<<dim3(16, 16), b256, 0, stream>>>(w_out, woutT,             512, 512);
  transpose_f16<<<dim3(64, 16), b256, 0, stream>>>(w_ff1, wff1T,             512, 2048);
  transpose_f16<<<dim3(16, 64), b256, 0, stream>>>(w_ff2, wff2T,             2048, 512);
  whash_f32<<<dim3(512, 2), b256, 0, stream>>>(w_qk, rot, WrT, ctr);
  // LN1: [hhi | hlo*64], row stride 1024
  ln_kernel<<<dim3(8192), b256, 0, stream>>>(x, ln1g, ln1b, hsplit, 1024, 1);
  // qkv = h1 @ [w_qk | w_v], head-major f16 out
  gemm_bt<7><<<dim3(8, 256), b256, 0, stream>>>(hsplit, 1024, wqkvT, 512, 512, 1024,
      nullptr, gqk, gv, nullptr, nullptr, nullptr);
  // approx hash (K=64 MFMA) + flag near-ties
  rhash_kernel<<<dim3(2048), b256, 0, stream>>>(gqk, rot, buckets, ctr, list);
  // exact fixup of flagged rows
  fixup_kernel<<<dim3(256), b256, 0, stream>>>(hsplit, WrT, ctr, list, buckets);
  sort_kernel<<<dim3(64), b256, 0, stream>>>(buckets, sticker);
  attn2_kernel<<<dim3(32, 64), b256, 0, stream>>>(gqk, gv, sticker, o_buf);
  // y1 (in d_out) = x + o @ w_out + b_out
  gemm_bt<2><<<dim3(4, 256), b256, 0, stream>>>(o_buf, 512, woutT, 512, 512, 512,
      out, nullptr, nullptr, b_out, x, nullptr);
  ln_kernel<<<dim3(8192), b256, 0, stream>>>(out, ln2g, ln2b, h2, 512, 0);
  // FFN in 2 row-chunks of 16384
  for (int c = 0; c < 2; ++c) {
    const long roff = (long)c * 16384;
    gemm_bt<3><<<dim3(16, 128), b256, 0, stream>>>(h2 + roff * 512, 512, wff1T, 512, 512, 2048,
        nullptr, abuf, nullptr, b_ff1, nullptr, nullptr);
    gemm_bt<4><<<dim3(4, 128), b256, 0, stream>>>(abuf, 2048, wff2T, 2048, 2048, 512,
        out + roff * 512, nullptr, nullptr, b_ff2, x + roff * 512, out + roff * 512);
  }
}